// Round 6
// baseline (834.718 us; speedup 1.0000x reference)
//
#include <hip/hip_runtime.h>
#include <hip/hip_fp16.h>

#define THREADS 256

// ---------------- preprocessing: degree, dinv, CSR build ----------------

__global__ void k_count(const int* __restrict__ ei, int* __restrict__ cnt, int E) {
    int e = blockIdx.x * blockDim.x + threadIdx.x;
    if (e < E) atomicAdd(&cnt[ei[E + e]], 1);   // dst = ei[1][e]
}

__global__ void k_dinv(const int* __restrict__ cnt, float* __restrict__ dinv, int N) {
    int n = blockIdx.x * blockDim.x + threadIdx.x;
    if (n < N) dinv[n] = rsqrtf((float)cnt[n] + 1.0f);  // +1 self loop
}

// block-level exclusive scan (Hillis-Steele in LDS) + block sums
__global__ void k_scan1(const int* __restrict__ cnt, int* __restrict__ rp,
                        int* __restrict__ bsum, int N) {
    __shared__ int s[THREADS];
    int tid = threadIdx.x;
    int i = blockIdx.x * THREADS + tid;
    int v = (i < N) ? cnt[i] : 0;
    s[tid] = v;
    __syncthreads();
    for (int d = 1; d < THREADS; d <<= 1) {
        int t = (tid >= d) ? s[tid - d] : 0;
        __syncthreads();
        s[tid] += t;
        __syncthreads();
    }
    if (i < N) rp[i] = s[tid] - v;              // exclusive
    if (tid == THREADS - 1) bsum[blockIdx.x] = s[tid];
}

// scan of block sums; requires nb <= THREADS (N=50000 -> nb=196, ok)
__global__ void k_scan2(int* __restrict__ bsum, int nb) {
    __shared__ int s[THREADS];
    int tid = threadIdx.x;
    int v = (tid < nb) ? bsum[tid] : 0;
    s[tid] = v;
    __syncthreads();
    for (int d = 1; d < THREADS; d <<= 1) {
        int t = (tid >= d) ? s[tid - d] : 0;
        __syncthreads();
        s[tid] += t;
        __syncthreads();
    }
    if (tid < nb) bsum[tid] = s[tid] - v;       // exclusive
}

__global__ void k_add(int* __restrict__ rp, const int* __restrict__ bsum, int N, int E) {
    int i = blockIdx.x * THREADS + threadIdx.x;
    if (i < N) rp[i] += bsum[blockIdx.x];
    if (i == 0) rp[N] = E;
}

// edge packet: .x = src index, .y = bitcast(norm weight)
__global__ void k_scatter(const int* __restrict__ ei, const int* __restrict__ rp,
                          int* __restrict__ fill, const float* __restrict__ dinv,
                          int2* __restrict__ epack, int E) {
    int e = blockIdx.x * blockDim.x + threadIdx.x;
    if (e >= E) return;
    int s = ei[e], d = ei[E + e];
    int pos = rp[d] + atomicAdd(&fill[d], 1);
    int2 p;
    p.x = s;
    p.y = __float_as_int(dinv[s] * dinv[d]);
    epack[pos] = p;
}

// ---------------- group sizes via sorted-batch boundary detection (no atomics) ----

__global__ void k_ginit(int* __restrict__ gstart, int N, int G) {
    int g = threadIdx.x;
    if (g < G) gstart[g] = N;
}

__global__ void k_gbound(const int* __restrict__ batch, int* __restrict__ gstart, int N) {
    int n = blockIdx.x * blockDim.x + threadIdx.x;
    if (n >= N) return;
    if (n == 0) gstart[batch[0]] = 0;
    else if (batch[n] != batch[n - 1]) gstart[batch[n]] = n;
}

// single block of 128 threads: suffix-min fix (empty groups), then counts
__global__ void k_gfix(const int* __restrict__ gstart, float* __restrict__ gcnt, int N, int G) {
    __shared__ int s[129];
    int g = threadIdx.x;                         // 0..127
    s[g] = gstart[g];
    if (g == 0) s[128] = N;
    __syncthreads();
    for (int d = 1; d < 128; d <<= 1) {
        int v = s[g];
        int w = (g + d <= 128) ? s[g + d] : N;
        __syncthreads();
        s[g] = min(v, w);
        __syncthreads();
    }
    int nxt = (g < 127) ? s[g + 1] : N;
    gcnt[g] = (float)(nxt - s[g]);
}

// ---------------- fp32 GEMM: Y[N,128] = X[N,128] @ W[128,128] ----------------
// Also emits an fp16 mirror Yh for the aggregation gather.

#define BM 64
#define BK 32

__global__ __launch_bounds__(256) void k_gemm(const float* __restrict__ X,
                                              const float* __restrict__ W,
                                              float* __restrict__ Y,
                                              __half* __restrict__ Yh, int N) {
    __shared__ float Xs[BK][BM + 1];   // transposed: Xs[k][m]
    __shared__ float Ws[BK][128];
    int tid = threadIdx.x;
    int tr = tid & 15, tc = tid >> 4;
    int r0 = tr * 4, c0 = tc * 8;
    int m0 = blockIdx.x * BM;

    float acc[4][8];
#pragma unroll
    for (int r = 0; r < 4; ++r)
#pragma unroll
        for (int c = 0; c < 8; ++c) acc[r][c] = 0.f;

    for (int k0 = 0; k0 < 128; k0 += BK) {
        __syncthreads();
#pragma unroll
        for (int i = 0; i < 2; ++i) {
            int idx = tid + 256 * i;             // 0..511
            int row = idx >> 3;                  // 0..63
            int kq  = idx & 7;
            float4 v = make_float4(0.f, 0.f, 0.f, 0.f);
            int grow = m0 + row;
            if (grow < N) v = *(const float4*)&X[(size_t)grow * 128 + k0 + kq * 4];
            Xs[kq * 4 + 0][row] = v.x;
            Xs[kq * 4 + 1][row] = v.y;
            Xs[kq * 4 + 2][row] = v.z;
            Xs[kq * 4 + 3][row] = v.w;
        }
#pragma unroll
        for (int i = 0; i < 4; ++i) {
            int idx = tid + 256 * i;             // 0..1023
            int krow = idx >> 5;
            int cq   = idx & 31;
            *(float4*)&Ws[krow][cq * 4] = *(const float4*)&W[(size_t)(k0 + krow) * 128 + cq * 4];
        }
        __syncthreads();

#pragma unroll
        for (int kk = 0; kk < BK; ++kk) {
            float4 a  = *(const float4*)&Xs[kk][r0];
            float4 b0 = *(const float4*)&Ws[kk][c0];
            float4 b1 = *(const float4*)&Ws[kk][c0 + 4];
            float av[4] = {a.x, a.y, a.z, a.w};
            float bv[8] = {b0.x, b0.y, b0.z, b0.w, b1.x, b1.y, b1.z, b1.w};
#pragma unroll
            for (int r = 0; r < 4; ++r)
#pragma unroll
                for (int c = 0; c < 8; ++c)
                    acc[r][c] = fmaf(av[r], bv[c], acc[r][c]);
        }
    }

#pragma unroll
    for (int r = 0; r < 4; ++r) {
        int row = m0 + r0 + r;
        if (row < N) {
            float4 o0 = make_float4(acc[r][0], acc[r][1], acc[r][2], acc[r][3]);
            float4 o1 = make_float4(acc[r][4], acc[r][5], acc[r][6], acc[r][7]);
            *(float4*)&Y[(size_t)row * 128 + c0]     = o0;
            *(float4*)&Y[(size_t)row * 128 + c0 + 4] = o1;
            __half hbuf[8];
#pragma unroll
            for (int c = 0; c < 8; ++c) hbuf[c] = __float2half(acc[r][c]);
            *(int4*)&Yh[(size_t)row * 128 + c0] = *(int4*)hbuf;   // 8 halves = 16B
        }
    }
}

// ---------------- aggregation ----------------
// One node per 64-lane wave; 4 edges per gather instruction:
//   slot = lane>>4 picks the edge, cg = lane&15 picks 16B (8 halves) of the row.
// 8-edge unrolled loop = 2 gather instructions/iter, wave-uniform trip count
// (clamped uniform packet index, per-slot weight zeroing -> no divergence).
// Butterfly shfl_xor(16,32) sums the 4 slot groups; lanes 0..15 finalize.

template <int POOL>
__global__ __launch_bounds__(256) void k_aggregate(const float* __restrict__ H,
                                                   const __half* __restrict__ Hh,
                                                   float* __restrict__ OUT,
                                                   const int* __restrict__ rp,
                                                   const int2* __restrict__ epack,
                                                   const float* __restrict__ dinv,
                                                   const float* __restrict__ bias,
                                                   const int* __restrict__ batch,
                                                   float* __restrict__ pooled, int N) {
    int wid  = threadIdx.x >> 6;
    int lane = threadIdx.x & 63;
    int n = blockIdx.x * 4 + wid;
    if (n >= N) return;
    int slot = lane >> 4;            // 0..3: edge within the quad
    int cg   = lane & 15;            // column group: cols cg*8 .. cg*8+7

    float acc[8];
#pragma unroll
    for (int i = 0; i < 8; ++i) acc[i] = 0.f;

    int beg = rp[n], end = rp[n + 1];
    int last = end - 1;

    for (int e = beg; e < end; e += 8) {
        int2 pk[8];
#pragma unroll
        for (int j = 0; j < 8; ++j) {
            int idx = e + j;
            pk[j] = epack[idx < end ? idx : last];   // uniform clamped address
        }
#pragma unroll
        for (int h = 0; h < 2; ++h) {
            // lane's packet: pk[h*4 + slot] via cndmask tree (static indices)
            int2 a = (slot & 2) ? ((slot & 1) ? pk[h * 4 + 3] : pk[h * 4 + 2])
                                : ((slot & 1) ? pk[h * 4 + 1] : pk[h * 4 + 0]);
            float w = (e + h * 4 + slot < end) ? __int_as_float(a.y) : 0.f;
            int4 raw = *(const int4*)&Hh[(size_t)a.x * 128 + cg * 8];  // 8 halves
            float2 f0 = __half22float2(*(__half2*)&raw.x);
            float2 f1 = __half22float2(*(__half2*)&raw.y);
            float2 f2 = __half22float2(*(__half2*)&raw.z);
            float2 f3 = __half22float2(*(__half2*)&raw.w);
            acc[0] = fmaf(w, f0.x, acc[0]); acc[1] = fmaf(w, f0.y, acc[1]);
            acc[2] = fmaf(w, f1.x, acc[2]); acc[3] = fmaf(w, f1.y, acc[3]);
            acc[4] = fmaf(w, f2.x, acc[4]); acc[5] = fmaf(w, f2.y, acc[5]);
            acc[6] = fmaf(w, f3.x, acc[6]); acc[7] = fmaf(w, f3.y, acc[7]);
        }
    }

    // sum the 4 slot groups (lanes l, l^16, l^32, l^48 share the same columns)
#pragma unroll
    for (int i = 0; i < 8; ++i) {
        acc[i] += __shfl_xor(acc[i], 16, 64);
        acc[i] += __shfl_xor(acc[i], 32, 64);
    }

    if (slot == 0) {                 // lanes 0..15 finalize cols cg*8..cg*8+7
        int c0 = cg * 8;
        float di = dinv[n];
        float sw = di * di;
        float4 hv0 = *(const float4*)&H[(size_t)n * 128 + c0];
        float4 hv1 = *(const float4*)&H[(size_t)n * 128 + c0 + 4];
        float4 bv0 = *(const float4*)&bias[c0];
        float4 bv1 = *(const float4*)&bias[c0 + 4];
        float4 o0, o1;
        o0.x = fmaxf(fmaf(sw, hv0.x, acc[0]) + bv0.x, 0.f);
        o0.y = fmaxf(fmaf(sw, hv0.y, acc[1]) + bv0.y, 0.f);
        o0.z = fmaxf(fmaf(sw, hv0.z, acc[2]) + bv0.z, 0.f);
        o0.w = fmaxf(fmaf(sw, hv0.w, acc[3]) + bv0.w, 0.f);
        o1.x = fmaxf(fmaf(sw, hv1.x, acc[4]) + bv1.x, 0.f);
        o1.y = fmaxf(fmaf(sw, hv1.y, acc[5]) + bv1.y, 0.f);
        o1.z = fmaxf(fmaf(sw, hv1.z, acc[6]) + bv1.z, 0.f);
        o1.w = fmaxf(fmaf(sw, hv1.w, acc[7]) + bv1.w, 0.f);
        if (POOL) {
            int g = batch[n];
            atomicAdd(&pooled[g * 128 + c0 + 0], o0.x);
            atomicAdd(&pooled[g * 128 + c0 + 1], o0.y);
            atomicAdd(&pooled[g * 128 + c0 + 2], o0.z);
            atomicAdd(&pooled[g * 128 + c0 + 3], o0.w);
            atomicAdd(&pooled[g * 128 + c0 + 4], o1.x);
            atomicAdd(&pooled[g * 128 + c0 + 5], o1.y);
            atomicAdd(&pooled[g * 128 + c0 + 6], o1.z);
            atomicAdd(&pooled[g * 128 + c0 + 7], o1.w);
        } else {
            *(float4*)&OUT[(size_t)n * 128 + c0]     = o0;
            *(float4*)&OUT[(size_t)n * 128 + c0 + 4] = o1;
        }
    }
}

// ---------------- final: out[G,64] = (pooled/cnt) @ lin_W + lin_b ----------------

__global__ void k_final(const float* __restrict__ pooled, const float* __restrict__ gcnt,
                        const float* __restrict__ lw, const float* __restrict__ lb,
                        float* __restrict__ out, int G) {
    int i = blockIdx.x * blockDim.x + threadIdx.x;
    if (i >= G * 64) return;
    int g = i >> 6, o = i & 63;
    float inv = 1.0f / fmaxf(gcnt[g], 1.0f);
    float acc = 0.f;
#pragma unroll
    for (int k = 0; k < 128; ++k) acc = fmaf(pooled[g * 128 + k], lw[k * 64 + o], acc);
    out[i] = acc * inv + lb[o];
}

// ---------------- launch ----------------

extern "C" void kernel_launch(void* const* d_in, const int* in_sizes, int n_in,
                              void* d_out, int out_size, void* d_ws, size_t ws_size,
                              hipStream_t stream) {
    const float* x   = (const float*)d_in[0];
    const int* ei    = (const int*)d_in[1];
    const int* batch = (const int*)d_in[2];
    const float* W0  = (const float*)d_in[3];
    const float* b0  = (const float*)d_in[4];
    const float* W1  = (const float*)d_in[5];
    const float* b1  = (const float*)d_in[6];
    const float* W2  = (const float*)d_in[7];
    const float* b2  = (const float*)d_in[8];
    const float* lw  = (const float*)d_in[9];
    const float* lb  = (const float*)d_in[10];
    float* out = (float*)d_out;

    const int N = in_sizes[2];        // 50000
    const int E = in_sizes[1] / 2;    // 600000
    const int G = 128;

    char* ws = (char*)d_ws;
    size_t off = 0;
    auto alloc = [&](size_t bytes) -> void* {
        void* p = ws + off;
        off += (bytes + 255) & ~(size_t)255;
        return p;
    };
    float*  hA     = (float*) alloc((size_t)N * 128 * 4);
    float*  hB     = (float*) alloc((size_t)N * 128 * 4);
    __half* hBh    = (__half*)alloc((size_t)N * 128 * 2);
    float*  dinv   = (float*) alloc((size_t)N * 4);
    int*    cnt    = (int*)   alloc((size_t)N * 4);
    int*    rp     = (int*)   alloc((size_t)(N + 1) * 4);
    int2*   epack  = (int2*)  alloc((size_t)E * 8);
    int*    bsum   = (int*)   alloc(1024 * 4);
    float*  pooled = (float*) alloc((size_t)G * 128 * 4);
    float*  gcnt   = (float*) alloc((size_t)G * 4);
    int*    gstart = (int*)   alloc((size_t)(G + 1) * 4);
    (void)ws_size; (void)n_in; (void)out_size;

    int nbN = (N + THREADS - 1) / THREADS;  // 196 (must be <= 256 for k_scan2)
    int nbE = (E + THREADS - 1) / THREADS;

    hipMemsetAsync(cnt, 0, (size_t)N * 4, stream);
    hipMemsetAsync(pooled, 0, (size_t)G * 128 * 4, stream);

    k_count<<<nbE, THREADS, 0, stream>>>(ei, cnt, E);
    k_dinv<<<nbN, THREADS, 0, stream>>>(cnt, dinv, N);
    k_scan1<<<nbN, THREADS, 0, stream>>>(cnt, rp, bsum, N);
    k_scan2<<<1, THREADS, 0, stream>>>(bsum, nbN);
    k_add<<<nbN, THREADS, 0, stream>>>(rp, bsum, N, E);
    hipMemsetAsync(cnt, 0, (size_t)N * 4, stream);   // reuse as fill counters
    k_scatter<<<nbE, THREADS, 0, stream>>>(ei, rp, cnt, dinv, epack, E);

    k_ginit<<<1, 128, 0, stream>>>(gstart, N, G);
    k_gbound<<<nbN, THREADS, 0, stream>>>(batch, gstart, N);
    k_gfix<<<1, 128, 0, stream>>>(gstart, gcnt, N, G);

    int gemm_grid = (N + BM - 1) / BM;
    int agg_grid  = (N + 3) / 4;

    k_gemm<<<gemm_grid, 256, 0, stream>>>(x, W0, hB, hBh, N);
    k_aggregate<0><<<agg_grid, 256, 0, stream>>>(hB, hBh, hA, rp, epack, dinv, b0, batch, pooled, N);
    k_gemm<<<gemm_grid, 256, 0, stream>>>(hA, W1, hB, hBh, N);
    k_aggregate<0><<<agg_grid, 256, 0, stream>>>(hB, hBh, hA, rp, epack, dinv, b1, batch, pooled, N);
    k_gemm<<<gemm_grid, 256, 0, stream>>>(hA, W2, hB, hBh, N);
    k_aggregate<1><<<agg_grid, 256, 0, stream>>>(hB, hBh, hA, rp, epack, dinv, b2, batch, pooled, N);
    k_final<<<(G * 64 + THREADS - 1) / THREADS, THREADS, 0, stream>>>(pooled, gcnt, lw, lb, out, G);
}

// Round 7
// 668.176 us; speedup vs baseline: 1.2492x; 1.2492x over previous
//
#include <hip/hip_runtime.h>
#include <hip/hip_fp16.h>

#define THREADS 256

// ---------------- preprocessing: degree, dinv, CSR build ----------------

__global__ void k_count(const int* __restrict__ ei, int* __restrict__ cnt, int E) {
    int e = blockIdx.x * blockDim.x + threadIdx.x;
    if (e < E) atomicAdd(&cnt[ei[E + e]], 1);   // dst = ei[1][e]
}

__global__ void k_dinv(const int* __restrict__ cnt, float* __restrict__ dinv, int N) {
    int n = blockIdx.x * blockDim.x + threadIdx.x;
    if (n < N) dinv[n] = rsqrtf((float)cnt[n] + 1.0f);  // +1 self loop
}

// block-level exclusive scan (Hillis-Steele in LDS) + block sums
__global__ void k_scan1(const int* __restrict__ cnt, int* __restrict__ rp,
                        int* __restrict__ bsum, int N) {
    __shared__ int s[THREADS];
    int tid = threadIdx.x;
    int i = blockIdx.x * THREADS + tid;
    int v = (i < N) ? cnt[i] : 0;
    s[tid] = v;
    __syncthreads();
    for (int d = 1; d < THREADS; d <<= 1) {
        int t = (tid >= d) ? s[tid - d] : 0;
        __syncthreads();
        s[tid] += t;
        __syncthreads();
    }
    if (i < N) rp[i] = s[tid] - v;              // exclusive
    if (tid == THREADS - 1) bsum[blockIdx.x] = s[tid];
}

// scan of block sums; requires nb <= THREADS (N=50000 -> nb=196, ok)
__global__ void k_scan2(int* __restrict__ bsum, int nb) {
    __shared__ int s[THREADS];
    int tid = threadIdx.x;
    int v = (tid < nb) ? bsum[tid] : 0;
    s[tid] = v;
    __syncthreads();
    for (int d = 1; d < THREADS; d <<= 1) {
        int t = (tid >= d) ? s[tid - d] : 0;
        __syncthreads();
        s[tid] += t;
        __syncthreads();
    }
    if (tid < nb) bsum[tid] = s[tid] - v;       // exclusive
}

__global__ void k_add(int* __restrict__ rp, const int* __restrict__ bsum, int N, int E) {
    int i = blockIdx.x * THREADS + threadIdx.x;
    if (i < N) rp[i] += bsum[blockIdx.x];
    if (i == 0) rp[N] = E;
}

// edge packet: .x = src index, .y = bitcast(norm weight)
__global__ void k_scatter(const int* __restrict__ ei, const int* __restrict__ rp,
                          int* __restrict__ fill, const float* __restrict__ dinv,
                          int2* __restrict__ epack, int E) {
    int e = blockIdx.x * blockDim.x + threadIdx.x;
    if (e >= E) return;
    int s = ei[e], d = ei[E + e];
    int pos = rp[d] + atomicAdd(&fill[d], 1);
    int2 p;
    p.x = s;
    p.y = __float_as_int(dinv[s] * dinv[d]);
    epack[pos] = p;
}

// ---------------- group sizes via sorted-batch boundary detection (no atomics) ----

__global__ void k_ginit(int* __restrict__ gstart, int N, int G) {
    int g = threadIdx.x;
    if (g < G) gstart[g] = N;
}

__global__ void k_gbound(const int* __restrict__ batch, int* __restrict__ gstart, int N) {
    int n = blockIdx.x * blockDim.x + threadIdx.x;
    if (n >= N) return;
    if (n == 0) gstart[batch[0]] = 0;
    else if (batch[n] != batch[n - 1]) gstart[batch[n]] = n;
}

// single block of 128 threads: suffix-min fix (empty groups), then counts
__global__ void k_gfix(const int* __restrict__ gstart, float* __restrict__ gcnt, int N, int G) {
    __shared__ int s[129];
    int g = threadIdx.x;                         // 0..127
    s[g] = gstart[g];
    if (g == 0) s[128] = N;
    __syncthreads();
    for (int d = 1; d < 128; d <<= 1) {
        int v = s[g];
        int w = (g + d <= 128) ? s[g + d] : N;
        __syncthreads();
        s[g] = min(v, w);
        __syncthreads();
    }
    int nxt = (g < 127) ? s[g + 1] : N;
    gcnt[g] = (float)(nxt - s[g]);
}

// ---------------- fp32 GEMM: Y[N,128] = X[N,128] @ W[128,128] ----------------
// Also emits an fp16 mirror Yh for the aggregation gather.

#define BM 64
#define BK 32

__global__ __launch_bounds__(256) void k_gemm(const float* __restrict__ X,
                                              const float* __restrict__ W,
                                              float* __restrict__ Y,
                                              __half* __restrict__ Yh, int N) {
    __shared__ float Xs[BK][BM + 1];   // transposed: Xs[k][m]
    __shared__ float Ws[BK][128];
    int tid = threadIdx.x;
    int tr = tid & 15, tc = tid >> 4;
    int r0 = tr * 4, c0 = tc * 8;
    int m0 = blockIdx.x * BM;

    float acc[4][8];
#pragma unroll
    for (int r = 0; r < 4; ++r)
#pragma unroll
        for (int c = 0; c < 8; ++c) acc[r][c] = 0.f;

    for (int k0 = 0; k0 < 128; k0 += BK) {
        __syncthreads();
#pragma unroll
        for (int i = 0; i < 2; ++i) {
            int idx = tid + 256 * i;             // 0..511
            int row = idx >> 3;                  // 0..63
            int kq  = idx & 7;
            float4 v = make_float4(0.f, 0.f, 0.f, 0.f);
            int grow = m0 + row;
            if (grow < N) v = *(const float4*)&X[(size_t)grow * 128 + k0 + kq * 4];
            Xs[kq * 4 + 0][row] = v.x;
            Xs[kq * 4 + 1][row] = v.y;
            Xs[kq * 4 + 2][row] = v.z;
            Xs[kq * 4 + 3][row] = v.w;
        }
#pragma unroll
        for (int i = 0; i < 4; ++i) {
            int idx = tid + 256 * i;             // 0..1023
            int krow = idx >> 5;
            int cq   = idx & 31;
            *(float4*)&Ws[krow][cq * 4] = *(const float4*)&W[(size_t)(k0 + krow) * 128 + cq * 4];
        }
        __syncthreads();

#pragma unroll
        for (int kk = 0; kk < BK; ++kk) {
            float4 a  = *(const float4*)&Xs[kk][r0];
            float4 b0 = *(const float4*)&Ws[kk][c0];
            float4 b1 = *(const float4*)&Ws[kk][c0 + 4];
            float av[4] = {a.x, a.y, a.z, a.w};
            float bv[8] = {b0.x, b0.y, b0.z, b0.w, b1.x, b1.y, b1.z, b1.w};
#pragma unroll
            for (int r = 0; r < 4; ++r)
#pragma unroll
                for (int c = 0; c < 8; ++c)
                    acc[r][c] = fmaf(av[r], bv[c], acc[r][c]);
        }
    }

#pragma unroll
    for (int r = 0; r < 4; ++r) {
        int row = m0 + r0 + r;
        if (row < N) {
            float4 o0 = make_float4(acc[r][0], acc[r][1], acc[r][2], acc[r][3]);
            float4 o1 = make_float4(acc[r][4], acc[r][5], acc[r][6], acc[r][7]);
            *(float4*)&Y[(size_t)row * 128 + c0]     = o0;
            *(float4*)&Y[(size_t)row * 128 + c0 + 4] = o1;
            __half hbuf[8];
#pragma unroll
            for (int c = 0; c < 8; ++c) hbuf[c] = __float2half(acc[r][c]);
            *(int4*)&Yh[(size_t)row * 128 + c0] = *(int4*)hbuf;   // 8 halves = 16B
        }
    }
}

// ---------------- aggregation ----------------
// One node per 64-lane wave; 4 edges per gather instruction:
//   slot = lane>>4 picks the edge, cg = lane&15 picks 16B (8 halves) of the row.
// NO register arrays (R6 spilled pk[8] to scratch: WRITE_SIZE 543MB) — each
// lane loads its own packet directly; 16-lane groups share the address.
// 8 edges per iteration = 2 packet loads + 2 gathers in flight.
// Butterfly shfl_xor(16,32) sums the 4 slot groups; lanes 0..15 finalize.

template <int POOL>
__global__ __launch_bounds__(256) void k_aggregate(const float* __restrict__ H,
                                                   const __half* __restrict__ Hh,
                                                   float* __restrict__ OUT,
                                                   const int* __restrict__ rp,
                                                   const int2* __restrict__ epack,
                                                   const float* __restrict__ dinv,
                                                   const float* __restrict__ bias,
                                                   const int* __restrict__ batch,
                                                   float* __restrict__ pooled, int N) {
    int wid  = threadIdx.x >> 6;
    int lane = threadIdx.x & 63;
    int n = blockIdx.x * 4 + wid;
    if (n >= N) return;
    int slot = lane >> 4;            // 0..3: edge within the quad
    int cg   = lane & 15;            // column group: cols cg*8 .. cg*8+7

    float acc[8];
#pragma unroll
    for (int i = 0; i < 8; ++i) acc[i] = 0.f;

    int beg = rp[n], end = rp[n + 1];
    int last = end - 1;

    for (int e = beg; e < end; e += 8) {
        int i0 = e + slot;
        int i1 = e + 4 + slot;
        int2 a0 = epack[i0 < end ? i0 : last];
        int2 a1 = epack[i1 < end ? i1 : last];
        float w0 = (i0 < end) ? __int_as_float(a0.y) : 0.f;
        float w1 = (i1 < end) ? __int_as_float(a1.y) : 0.f;
        int4 r0 = *(const int4*)&Hh[(size_t)a0.x * 128 + cg * 8];  // 8 halves
        int4 r1 = *(const int4*)&Hh[(size_t)a1.x * 128 + cg * 8];

        float2 f;
        f = __half22float2(*(__half2*)&r0.x); acc[0] = fmaf(w0, f.x, acc[0]); acc[1] = fmaf(w0, f.y, acc[1]);
        f = __half22float2(*(__half2*)&r0.y); acc[2] = fmaf(w0, f.x, acc[2]); acc[3] = fmaf(w0, f.y, acc[3]);
        f = __half22float2(*(__half2*)&r0.z); acc[4] = fmaf(w0, f.x, acc[4]); acc[5] = fmaf(w0, f.y, acc[5]);
        f = __half22float2(*(__half2*)&r0.w); acc[6] = fmaf(w0, f.x, acc[6]); acc[7] = fmaf(w0, f.y, acc[7]);
        f = __half22float2(*(__half2*)&r1.x); acc[0] = fmaf(w1, f.x, acc[0]); acc[1] = fmaf(w1, f.y, acc[1]);
        f = __half22float2(*(__half2*)&r1.y); acc[2] = fmaf(w1, f.x, acc[2]); acc[3] = fmaf(w1, f.y, acc[3]);
        f = __half22float2(*(__half2*)&r1.z); acc[4] = fmaf(w1, f.x, acc[4]); acc[5] = fmaf(w1, f.y, acc[5]);
        f = __half22float2(*(__half2*)&r1.w); acc[6] = fmaf(w1, f.x, acc[6]); acc[7] = fmaf(w1, f.y, acc[7]);
    }

    // sum the 4 slot groups (lanes l, l^16, l^32, l^48 share the same columns)
#pragma unroll
    for (int i = 0; i < 8; ++i) {
        acc[i] += __shfl_xor(acc[i], 16, 64);
        acc[i] += __shfl_xor(acc[i], 32, 64);
    }

    if (slot == 0) {                 // lanes 0..15 finalize cols cg*8..cg*8+7
        int c0 = cg * 8;
        float di = dinv[n];
        float sw = di * di;
        float4 hv0 = *(const float4*)&H[(size_t)n * 128 + c0];
        float4 hv1 = *(const float4*)&H[(size_t)n * 128 + c0 + 4];
        float4 bv0 = *(const float4*)&bias[c0];
        float4 bv1 = *(const float4*)&bias[c0 + 4];
        float4 o0, o1;
        o0.x = fmaxf(fmaf(sw, hv0.x, acc[0]) + bv0.x, 0.f);
        o0.y = fmaxf(fmaf(sw, hv0.y, acc[1]) + bv0.y, 0.f);
        o0.z = fmaxf(fmaf(sw, hv0.z, acc[2]) + bv0.z, 0.f);
        o0.w = fmaxf(fmaf(sw, hv0.w, acc[3]) + bv0.w, 0.f);
        o1.x = fmaxf(fmaf(sw, hv1.x, acc[4]) + bv1.x, 0.f);
        o1.y = fmaxf(fmaf(sw, hv1.y, acc[5]) + bv1.y, 0.f);
        o1.z = fmaxf(fmaf(sw, hv1.z, acc[6]) + bv1.z, 0.f);
        o1.w = fmaxf(fmaf(sw, hv1.w, acc[7]) + bv1.w, 0.f);
        if (POOL) {
            int g = batch[n];
            atomicAdd(&pooled[g * 128 + c0 + 0], o0.x);
            atomicAdd(&pooled[g * 128 + c0 + 1], o0.y);
            atomicAdd(&pooled[g * 128 + c0 + 2], o0.z);
            atomicAdd(&pooled[g * 128 + c0 + 3], o0.w);
            atomicAdd(&pooled[g * 128 + c0 + 4], o1.x);
            atomicAdd(&pooled[g * 128 + c0 + 5], o1.y);
            atomicAdd(&pooled[g * 128 + c0 + 6], o1.z);
            atomicAdd(&pooled[g * 128 + c0 + 7], o1.w);
        } else {
            *(float4*)&OUT[(size_t)n * 128 + c0]     = o0;
            *(float4*)&OUT[(size_t)n * 128 + c0 + 4] = o1;
        }
    }
}

// ---------------- final: out[G,64] = (pooled/cnt) @ lin_W + lin_b ----------------

__global__ void k_final(const float* __restrict__ pooled, const float* __restrict__ gcnt,
                        const float* __restrict__ lw, const float* __restrict__ lb,
                        float* __restrict__ out, int G) {
    int i = blockIdx.x * blockDim.x + threadIdx.x;
    if (i >= G * 64) return;
    int g = i >> 6, o = i & 63;
    float inv = 1.0f / fmaxf(gcnt[g], 1.0f);
    float acc = 0.f;
#pragma unroll
    for (int k = 0; k < 128; ++k) acc = fmaf(pooled[g * 128 + k], lw[k * 64 + o], acc);
    out[i] = acc * inv + lb[o];
}

// ---------------- launch ----------------

extern "C" void kernel_launch(void* const* d_in, const int* in_sizes, int n_in,
                              void* d_out, int out_size, void* d_ws, size_t ws_size,
                              hipStream_t stream) {
    const float* x   = (const float*)d_in[0];
    const int* ei    = (const int*)d_in[1];
    const int* batch = (const int*)d_in[2];
    const float* W0  = (const float*)d_in[3];
    const float* b0  = (const float*)d_in[4];
    const float* W1  = (const float*)d_in[5];
    const float* b1  = (const float*)d_in[6];
    const float* W2  = (const float*)d_in[7];
    const float* b2  = (const float*)d_in[8];
    const float* lw  = (const float*)d_in[9];
    const float* lb  = (const float*)d_in[10];
    float* out = (float*)d_out;

    const int N = in_sizes[2];        // 50000
    const int E = in_sizes[1] / 2;    // 600000
    const int G = 128;

    char* ws = (char*)d_ws;
    size_t off = 0;
    auto alloc = [&](size_t bytes) -> void* {
        void* p = ws + off;
        off += (bytes + 255) & ~(size_t)255;
        return p;
    };
    float*  hA     = (float*) alloc((size_t)N * 128 * 4);
    float*  hB     = (float*) alloc((size_t)N * 128 * 4);
    __half* hBh    = (__half*)alloc((size_t)N * 128 * 2);
    float*  dinv   = (float*) alloc((size_t)N * 4);
    int*    cnt    = (int*)   alloc((size_t)N * 4);
    int*    rp     = (int*)   alloc((size_t)(N + 1) * 4);
    int2*   epack  = (int2*)  alloc((size_t)E * 8);
    int*    bsum   = (int*)   alloc(1024 * 4);
    float*  pooled = (float*) alloc((size_t)G * 128 * 4);
    float*  gcnt   = (float*) alloc((size_t)G * 4);
    int*    gstart = (int*)   alloc((size_t)(G + 1) * 4);
    (void)ws_size; (void)n_in; (void)out_size;

    int nbN = (N + THREADS - 1) / THREADS;  // 196 (must be <= 256 for k_scan2)
    int nbE = (E + THREADS - 1) / THREADS;

    hipMemsetAsync(cnt, 0, (size_t)N * 4, stream);
    hipMemsetAsync(pooled, 0, (size_t)G * 128 * 4, stream);

    k_count<<<nbE, THREADS, 0, stream>>>(ei, cnt, E);
    k_dinv<<<nbN, THREADS, 0, stream>>>(cnt, dinv, N);
    k_scan1<<<nbN, THREADS, 0, stream>>>(cnt, rp, bsum, N);
    k_scan2<<<1, THREADS, 0, stream>>>(bsum, nbN);
    k_add<<<nbN, THREADS, 0, stream>>>(rp, bsum, N, E);
    hipMemsetAsync(cnt, 0, (size_t)N * 4, stream);   // reuse as fill counters
    k_scatter<<<nbE, THREADS, 0, stream>>>(ei, rp, cnt, dinv, epack, E);

    k_ginit<<<1, 128, 0, stream>>>(gstart, N, G);
    k_gbound<<<nbN, THREADS, 0, stream>>>(batch, gstart, N);
    k_gfix<<<1, 128, 0, stream>>>(gstart, gcnt, N, G);

    int gemm_grid = (N + BM - 1) / BM;
    int agg_grid  = (N + 3) / 4;

    k_gemm<<<gemm_grid, 256, 0, stream>>>(x, W0, hB, hBh, N);
    k_aggregate<0><<<agg_grid, 256, 0, stream>>>(hB, hBh, hA, rp, epack, dinv, b0, batch, pooled, N);
    k_gemm<<<gemm_grid, 256, 0, stream>>>(hA, W1, hB, hBh, N);
    k_aggregate<0><<<agg_grid, 256, 0, stream>>>(hB, hBh, hA, rp, epack, dinv, b1, batch, pooled, N);
    k_gemm<<<gemm_grid, 256, 0, stream>>>(hA, W2, hB, hBh, N);
    k_aggregate<1><<<agg_grid, 256, 0, stream>>>(hB, hBh, hA, rp, epack, dinv, b2, batch, pooled, N);
    k_final<<<(G * 64 + THREADS - 1) / THREADS, THREADS, 0, stream>>>(pooled, gcnt, lw, lb, out, G);
}

// Round 8
// 350.028 us; speedup vs baseline: 2.3847x; 1.9089x over previous
//
#include <hip/hip_runtime.h>
#include <hip/hip_fp16.h>

#define THREADS 256

// ---------------- preprocessing: degree, dinv, CSR build ----------------

__global__ void k_count(const int* __restrict__ ei, int* __restrict__ cnt, int E) {
    int e = blockIdx.x * blockDim.x + threadIdx.x;
    if (e < E) atomicAdd(&cnt[ei[E + e]], 1);   // dst = ei[1][e]
}

__global__ void k_dinv(const int* __restrict__ cnt, float* __restrict__ dinv, int N) {
    int n = blockIdx.x * blockDim.x + threadIdx.x;
    if (n < N) dinv[n] = rsqrtf((float)cnt[n] + 1.0f);  // +1 self loop
}

// block-level exclusive scan (Hillis-Steele in LDS) + block sums
__global__ void k_scan1(const int* __restrict__ cnt, int* __restrict__ rp,
                        int* __restrict__ bsum, int N) {
    __shared__ int s[THREADS];
    int tid = threadIdx.x;
    int i = blockIdx.x * THREADS + tid;
    int v = (i < N) ? cnt[i] : 0;
    s[tid] = v;
    __syncthreads();
    for (int d = 1; d < THREADS; d <<= 1) {
        int t = (tid >= d) ? s[tid - d] : 0;
        __syncthreads();
        s[tid] += t;
        __syncthreads();
    }
    if (i < N) rp[i] = s[tid] - v;              // exclusive
    if (tid == THREADS - 1) bsum[blockIdx.x] = s[tid];
}

// scan of block sums; requires nb <= THREADS (N=50000 -> nb=196, ok)
__global__ void k_scan2(int* __restrict__ bsum, int nb) {
    __shared__ int s[THREADS];
    int tid = threadIdx.x;
    int v = (tid < nb) ? bsum[tid] : 0;
    s[tid] = v;
    __syncthreads();
    for (int d = 1; d < THREADS; d <<= 1) {
        int t = (tid >= d) ? s[tid - d] : 0;
        __syncthreads();
        s[tid] += t;
        __syncthreads();
    }
    if (tid < nb) bsum[tid] = s[tid] - v;       // exclusive
}

__global__ void k_add(int* __restrict__ rp, const int* __restrict__ bsum, int N, int E) {
    int i = blockIdx.x * THREADS + threadIdx.x;
    if (i < N) rp[i] += bsum[blockIdx.x];
    if (i == 0) rp[N] = E;
}

// edge packet: .x = src index, .y = bitcast(norm weight)
__global__ void k_scatter(const int* __restrict__ ei, const int* __restrict__ rp,
                          int* __restrict__ fill, const float* __restrict__ dinv,
                          int2* __restrict__ epack, int E) {
    int e = blockIdx.x * blockDim.x + threadIdx.x;
    if (e >= E) return;
    int s = ei[e], d = ei[E + e];
    int pos = rp[d] + atomicAdd(&fill[d], 1);
    int2 p;
    p.x = s;
    p.y = __float_as_int(dinv[s] * dinv[d]);
    epack[pos] = p;
}

// ---------------- group sizes via sorted-batch boundary detection (no atomics) ----

__global__ void k_ginit(int* __restrict__ gstart, int N, int G) {
    int g = threadIdx.x;
    if (g < G) gstart[g] = N;
}

__global__ void k_gbound(const int* __restrict__ batch, int* __restrict__ gstart, int N) {
    int n = blockIdx.x * blockDim.x + threadIdx.x;
    if (n >= N) return;
    if (n == 0) gstart[batch[0]] = 0;
    else if (batch[n] != batch[n - 1]) gstart[batch[n]] = n;
}

// single block of 128 threads: suffix-min fix (empty groups), then counts
__global__ void k_gfix(const int* __restrict__ gstart, float* __restrict__ gcnt, int N, int G) {
    __shared__ int s[129];
    int g = threadIdx.x;                         // 0..127
    s[g] = gstart[g];
    if (g == 0) s[128] = N;
    __syncthreads();
    for (int d = 1; d < 128; d <<= 1) {
        int v = s[g];
        int w = (g + d <= 128) ? s[g + d] : N;
        __syncthreads();
        s[g] = min(v, w);
        __syncthreads();
    }
    int nxt = (g < 127) ? s[g + 1] : N;
    gcnt[g] = (float)(nxt - s[g]);
}

// ---------------- fp32 GEMM: Y[N,128] = X[N,128] @ W[128,128] ----------------
// Also emits an fp16 mirror Yh for the aggregation gather.

#define BM 64
#define BK 32

__global__ __launch_bounds__(256) void k_gemm(const float* __restrict__ X,
                                              const float* __restrict__ W,
                                              float* __restrict__ Y,
                                              __half* __restrict__ Yh, int N) {
    __shared__ float Xs[BK][BM + 1];   // transposed: Xs[k][m]
    __shared__ float Ws[BK][128];
    int tid = threadIdx.x;
    int tr = tid & 15, tc = tid >> 4;
    int r0 = tr * 4, c0 = tc * 8;
    int m0 = blockIdx.x * BM;

    float acc[4][8];
#pragma unroll
    for (int r = 0; r < 4; ++r)
#pragma unroll
        for (int c = 0; c < 8; ++c) acc[r][c] = 0.f;

    for (int k0 = 0; k0 < 128; k0 += BK) {
        __syncthreads();
#pragma unroll
        for (int i = 0; i < 2; ++i) {
            int idx = tid + 256 * i;             // 0..511
            int row = idx >> 3;                  // 0..63
            int kq  = idx & 7;
            float4 v = make_float4(0.f, 0.f, 0.f, 0.f);
            int grow = m0 + row;
            if (grow < N) v = *(const float4*)&X[(size_t)grow * 128 + k0 + kq * 4];
            Xs[kq * 4 + 0][row] = v.x;
            Xs[kq * 4 + 1][row] = v.y;
            Xs[kq * 4 + 2][row] = v.z;
            Xs[kq * 4 + 3][row] = v.w;
        }
#pragma unroll
        for (int i = 0; i < 4; ++i) {
            int idx = tid + 256 * i;             // 0..1023
            int krow = idx >> 5;
            int cq   = idx & 31;
            *(float4*)&Ws[krow][cq * 4] = *(const float4*)&W[(size_t)(k0 + krow) * 128 + cq * 4];
        }
        __syncthreads();

#pragma unroll
        for (int kk = 0; kk < BK; ++kk) {
            float4 a  = *(const float4*)&Xs[kk][r0];
            float4 b0 = *(const float4*)&Ws[kk][c0];
            float4 b1 = *(const float4*)&Ws[kk][c0 + 4];
            float av[4] = {a.x, a.y, a.z, a.w};
            float bv[8] = {b0.x, b0.y, b0.z, b0.w, b1.x, b1.y, b1.z, b1.w};
#pragma unroll
            for (int r = 0; r < 4; ++r)
#pragma unroll
                for (int c = 0; c < 8; ++c)
                    acc[r][c] = fmaf(av[r], bv[c], acc[r][c]);
        }
    }

#pragma unroll
    for (int r = 0; r < 4; ++r) {
        int row = m0 + r0 + r;
        if (row < N) {
            float4 o0 = make_float4(acc[r][0], acc[r][1], acc[r][2], acc[r][3]);
            float4 o1 = make_float4(acc[r][4], acc[r][5], acc[r][6], acc[r][7]);
            *(float4*)&Y[(size_t)row * 128 + c0]     = o0;
            *(float4*)&Y[(size_t)row * 128 + c0 + 4] = o1;
            __half hbuf[8];
#pragma unroll
            for (int c = 0; c < 8; ++c) hbuf[c] = __float2half(acc[r][c]);
            *(int4*)&Yh[(size_t)row * 128 + c0] = *(int4*)hbuf;   // 8 halves = 16B
        }
    }
}

// ---------------- aggregation ----------------
// R5 structure (proven 121us): one node per 64-lane wave, __half2 per lane,
// one full 256B row per gather instruction. R8 change: 8-deep unroll with
// NAMED scalar packets (no arrays -> no scratch; R6/R7 lesson) so 8 row
// gathers are in flight per iteration instead of 4.

template <int POOL>
__global__ __launch_bounds__(256) void k_aggregate(const float* __restrict__ H,
                                                   const __half* __restrict__ Hh,
                                                   float* __restrict__ OUT,
                                                   const int* __restrict__ rp,
                                                   const int2* __restrict__ epack,
                                                   const float* __restrict__ dinv,
                                                   const float* __restrict__ bias,
                                                   const int* __restrict__ batch,
                                                   float* __restrict__ pooled, int N) {
    int wid  = threadIdx.x >> 6;
    int lane = threadIdx.x & 63;
    int n = blockIdx.x * 4 + wid;
    if (n >= N) return;
    int c0 = lane * 2;

    float2 acc = make_float2(0.f, 0.f);
    int beg = rp[n], end = rp[n + 1];
    int last = end - 1;

    for (int e = beg; e < end; e += 8) {
        // 8 uniform packet loads (clamped tail), all independent
        int2 p0 = epack[e];
        int2 p1 = epack[min(e + 1, last)];
        int2 p2 = epack[min(e + 2, last)];
        int2 p3 = epack[min(e + 3, last)];
        int2 p4 = epack[min(e + 4, last)];
        int2 p5 = epack[min(e + 5, last)];
        int2 p6 = epack[min(e + 6, last)];
        int2 p7 = epack[min(e + 7, last)];
        float w0 = __int_as_float(p0.y);
        float w1 = (e + 1 < end) ? __int_as_float(p1.y) : 0.f;
        float w2 = (e + 2 < end) ? __int_as_float(p2.y) : 0.f;
        float w3 = (e + 3 < end) ? __int_as_float(p3.y) : 0.f;
        float w4 = (e + 4 < end) ? __int_as_float(p4.y) : 0.f;
        float w5 = (e + 5 < end) ? __int_as_float(p5.y) : 0.f;
        float w6 = (e + 6 < end) ? __int_as_float(p6.y) : 0.f;
        float w7 = (e + 7 < end) ? __int_as_float(p7.y) : 0.f;
        // 8 independent row gathers in flight
        __half2 h0 = *(const __half2*)&Hh[(size_t)p0.x * 128 + c0];
        __half2 h1 = *(const __half2*)&Hh[(size_t)p1.x * 128 + c0];
        __half2 h2 = *(const __half2*)&Hh[(size_t)p2.x * 128 + c0];
        __half2 h3 = *(const __half2*)&Hh[(size_t)p3.x * 128 + c0];
        __half2 h4 = *(const __half2*)&Hh[(size_t)p4.x * 128 + c0];
        __half2 h5 = *(const __half2*)&Hh[(size_t)p5.x * 128 + c0];
        __half2 h6 = *(const __half2*)&Hh[(size_t)p6.x * 128 + c0];
        __half2 h7 = *(const __half2*)&Hh[(size_t)p7.x * 128 + c0];
        float2 f;
        f = __half22float2(h0); acc.x = fmaf(w0, f.x, acc.x); acc.y = fmaf(w0, f.y, acc.y);
        f = __half22float2(h1); acc.x = fmaf(w1, f.x, acc.x); acc.y = fmaf(w1, f.y, acc.y);
        f = __half22float2(h2); acc.x = fmaf(w2, f.x, acc.x); acc.y = fmaf(w2, f.y, acc.y);
        f = __half22float2(h3); acc.x = fmaf(w3, f.x, acc.x); acc.y = fmaf(w3, f.y, acc.y);
        f = __half22float2(h4); acc.x = fmaf(w4, f.x, acc.x); acc.y = fmaf(w4, f.y, acc.y);
        f = __half22float2(h5); acc.x = fmaf(w5, f.x, acc.x); acc.y = fmaf(w5, f.y, acc.y);
        f = __half22float2(h6); acc.x = fmaf(w6, f.x, acc.x); acc.y = fmaf(w6, f.y, acc.y);
        f = __half22float2(h7); acc.x = fmaf(w7, f.x, acc.x); acc.y = fmaf(w7, f.y, acc.y);
    }

    float di = dinv[n];
    float sw = di * di;
    float2 hv = *(const float2*)&H[(size_t)n * 128 + c0];
    acc.x = fmaf(sw, hv.x, acc.x);
    acc.y = fmaf(sw, hv.y, acc.y);
    acc.x = fmaxf(acc.x + bias[c0], 0.f);
    acc.y = fmaxf(acc.y + bias[c0 + 1], 0.f);

    if (POOL) {
        int g = batch[n];
        atomicAdd(&pooled[g * 128 + c0], acc.x);
        atomicAdd(&pooled[g * 128 + c0 + 1], acc.y);
    } else {
        float2 o; o.x = acc.x; o.y = acc.y;
        *(float2*)&OUT[(size_t)n * 128 + c0] = o;
    }
}

// ---------------- final: out[G,64] = (pooled/cnt) @ lin_W + lin_b ----------------

__global__ void k_final(const float* __restrict__ pooled, const float* __restrict__ gcnt,
                        const float* __restrict__ lw, const float* __restrict__ lb,
                        float* __restrict__ out, int G) {
    int i = blockIdx.x * blockDim.x + threadIdx.x;
    if (i >= G * 64) return;
    int g = i >> 6, o = i & 63;
    float inv = 1.0f / fmaxf(gcnt[g], 1.0f);
    float acc = 0.f;
#pragma unroll
    for (int k = 0; k < 128; ++k) acc = fmaf(pooled[g * 128 + k], lw[k * 64 + o], acc);
    out[i] = acc * inv + lb[o];
}

// ---------------- launch ----------------

extern "C" void kernel_launch(void* const* d_in, const int* in_sizes, int n_in,
                              void* d_out, int out_size, void* d_ws, size_t ws_size,
                              hipStream_t stream) {
    const float* x   = (const float*)d_in[0];
    const int* ei    = (const int*)d_in[1];
    const int* batch = (const int*)d_in[2];
    const float* W0  = (const float*)d_in[3];
    const float* b0  = (const float*)d_in[4];
    const float* W1  = (const float*)d_in[5];
    const float* b1  = (const float*)d_in[6];
    const float* W2  = (const float*)d_in[7];
    const float* b2  = (const float*)d_in[8];
    const float* lw  = (const float*)d_in[9];
    const float* lb  = (const float*)d_in[10];
    float* out = (float*)d_out;

    const int N = in_sizes[2];        // 50000
    const int E = in_sizes[1] / 2;    // 600000
    const int G = 128;

    char* ws = (char*)d_ws;
    size_t off = 0;
    auto alloc = [&](size_t bytes) -> void* {
        void* p = ws + off;
        off += (bytes + 255) & ~(size_t)255;
        return p;
    };
    float*  hA     = (float*) alloc((size_t)N * 128 * 4);
    float*  hB     = (float*) alloc((size_t)N * 128 * 4);
    __half* hBh    = (__half*)alloc((size_t)N * 128 * 2);
    float*  dinv   = (float*) alloc((size_t)N * 4);
    int*    cnt    = (int*)   alloc((size_t)N * 4);
    int*    rp     = (int*)   alloc((size_t)(N + 1) * 4);
    int2*   epack  = (int2*)  alloc((size_t)E * 8);
    int*    bsum   = (int*)   alloc(1024 * 4);
    float*  pooled = (float*) alloc((size_t)G * 128 * 4);
    float*  gcnt   = (float*) alloc((size_t)G * 4);
    int*    gstart = (int*)   alloc((size_t)(G + 1) * 4);
    (void)ws_size; (void)n_in; (void)out_size;

    int nbN = (N + THREADS - 1) / THREADS;  // 196 (must be <= 256 for k_scan2)
    int nbE = (E + THREADS - 1) / THREADS;

    hipMemsetAsync(cnt, 0, (size_t)N * 4, stream);
    hipMemsetAsync(pooled, 0, (size_t)G * 128 * 4, stream);

    k_count<<<nbE, THREADS, 0, stream>>>(ei, cnt, E);
    k_dinv<<<nbN, THREADS, 0, stream>>>(cnt, dinv, N);
    k_scan1<<<nbN, THREADS, 0, stream>>>(cnt, rp, bsum, N);
    k_scan2<<<1, THREADS, 0, stream>>>(bsum, nbN);
    k_add<<<nbN, THREADS, 0, stream>>>(rp, bsum, N, E);
    hipMemsetAsync(cnt, 0, (size_t)N * 4, stream);   // reuse as fill counters
    k_scatter<<<nbE, THREADS, 0, stream>>>(ei, rp, cnt, dinv, epack, E);

    k_ginit<<<1, 128, 0, stream>>>(gstart, N, G);
    k_gbound<<<nbN, THREADS, 0, stream>>>(batch, gstart, N);
    k_gfix<<<1, 128, 0, stream>>>(gstart, gcnt, N, G);

    int gemm_grid = (N + BM - 1) / BM;
    int agg_grid  = (N + 3) / 4;

    k_gemm<<<gemm_grid, 256, 0, stream>>>(x, W0, hB, hBh, N);
    k_aggregate<0><<<agg_grid, 256, 0, stream>>>(hB, hBh, hA, rp, epack, dinv, b0, batch, pooled, N);
    k_gemm<<<gemm_grid, 256, 0, stream>>>(hA, W1, hB, hBh, N);
    k_aggregate<0><<<agg_grid, 256, 0, stream>>>(hB, hBh, hA, rp, epack, dinv, b1, batch, pooled, N);
    k_gemm<<<gemm_grid, 256, 0, stream>>>(hA, W2, hB, hBh, N);
    k_aggregate<1><<<agg_grid, 256, 0, stream>>>(hB, hBh, hA, rp, epack, dinv, b2, batch, pooled, N);
    k_final<<<(G * 64 + THREADS - 1) / THREADS, THREADS, 0, stream>>>(pooled, gcnt, lw, lb, out, G);
}